// Round 8
// baseline (319.773 us; speedup 1.0000x reference)
//
#include <hip/hip_runtime.h>
#include <math.h>

#define NROWS 200000
#define DCOLS 512
#define NC 3
#define SGRID 2048
#define NFULL 196608       // 6 full steps * SGRID*16 rows
#define TAILB 212          // (NROWS-NFULL)/16 blocks cover tail exactly
#define CGRID 2048

typedef float f4 __attribute__((ext_vector_type(4)));

__device__ __forceinline__ float elu1(float x) {
    return x > 0.0f ? x : __expf(x) - 1.0f;
}

__global__ void zero_sums(float* sums) {
    int t = blockIdx.x * blockDim.x + threadIdx.x;
    if (t < NC * DCOLS) sums[t] = 0.0f;
}

// 8 contiguous independent rows in flight per thread (32 load VGPRs, ~60
// total -> 2x the resident waves of BODY16). Labels first, then the burst
// of 8 global_load_dwordx4, then wave-uniform accumulate branches.
#define BODY8(base)                                                          \
    {                                                                        \
        int lb[8]; f4 v[8];                                                  \
        _Pragma("unroll") for (int j = 0; j < 8; ++j)                        \
            lb[j] = labels[(base) + j];                                      \
        _Pragma("unroll") for (int j = 0; j < 8; ++j)                        \
            v[j] = *(const f4*)(pbase + (size_t)((base) + j) * DCOLS);       \
        _Pragma("unroll") for (int j = 0; j < 8; ++j) {                      \
            f4 x = v[j];                                                     \
            if (tr) { x.x = elu1(w4.x * x.x); x.y = elu1(w4.y * x.y);        \
                      x.z = elu1(w4.z * x.z); x.w = elu1(w4.w * x.w); }      \
            if (lb[j] == 0)      a0 += x;                                    \
            else if (lb[j] == 1) a1 += x;                                    \
            else                 a2 += x;                                    \
        }                                                                    \
    }

__global__ __launch_bounds__(256) void segsum_kernel(
        const float* __restrict__ feature, const float* __restrict__ seq,
        const float* __restrict__ weight, const int* __restrict__ labels,
        const int* __restrict__ train, float* __restrict__ sums) {
    const int t = threadIdx.x;
    const int c4 = (t & 127) << 2;   // column base (4 floats)
    const int h  = t >> 7;           // wave-uniform half id
    const int tr = train[0];
    f4 w4 = (f4)(0.f);
    if (tr) w4 = *(const f4*)(weight + c4);
    const float* __restrict__ src = tr ? seq : feature;
    const float* pbase = src + c4;
    f4 a0 = (f4)(0.f), a1 = (f4)(0.f), a2 = (f4)(0.f);

    // block covers 16 contiguous rows per step; half h owns 8 of them
    for (int base = blockIdx.x * 16 + h * 8; base < NFULL; base += SGRID * 16)
        BODY8(base);
    if (blockIdx.x < TAILB)
        BODY8(NFULL + blockIdx.x * 16 + h * 8);

    // halves-reduce in LDS, then one atomicAdd per (class,col) per block
    __shared__ float red[NC][128][4];
    const int c = t & 127;
    if (h == 1) {
        *(f4*)red[0][c] = a0;
        *(f4*)red[1][c] = a1;
        *(f4*)red[2][c] = a2;
    }
    __syncthreads();
    if (h == 0) {
        a0 += *(const f4*)red[0][c];
        a1 += *(const f4*)red[1][c];
        a2 += *(const f4*)red[2][c];
        atomicAdd(&sums[0 * DCOLS + c4 + 0], a0.x);
        atomicAdd(&sums[0 * DCOLS + c4 + 1], a0.y);
        atomicAdd(&sums[0 * DCOLS + c4 + 2], a0.z);
        atomicAdd(&sums[0 * DCOLS + c4 + 3], a0.w);
        atomicAdd(&sums[1 * DCOLS + c4 + 0], a1.x);
        atomicAdd(&sums[1 * DCOLS + c4 + 1], a1.y);
        atomicAdd(&sums[1 * DCOLS + c4 + 2], a1.z);
        atomicAdd(&sums[1 * DCOLS + c4 + 3], a1.w);
        atomicAdd(&sums[2 * DCOLS + c4 + 0], a2.x);
        atomicAdd(&sums[2 * DCOLS + c4 + 1], a2.y);
        atomicAdd(&sums[2 * DCOLS + c4 + 2], a2.z);
        atomicAdd(&sums[2 * DCOLS + c4 + 3], a2.w);
    }
}

// ave = sums / (N/2); an[c] = ||ave[c]||. Single block.
__global__ __launch_bounds__(256) void ave_norm_kernel(
        const float* __restrict__ sums, float* __restrict__ ave,
        float* __restrict__ an) {
    __shared__ float red[4];
    const int t = threadIdx.x, lane = t & 63, wv = t >> 6;
    const float inv = 1.0f / (float)(NROWS / 2);
    for (int c = 0; c < NC; ++c) {
        float p = 0.0f;
        for (int j = t; j < DCOLS; j += 256) {
            float v = sums[c * DCOLS + j] * inv;
            ave[c * DCOLS + j] = v;
            p += v * v;
        }
        for (int o = 32; o; o >>= 1) p += __shfl_xor(p, o);
        if (lane == 0) red[wv] = p;
        __syncthreads();
        if (t == 0) an[c] = sqrtf(red[0] + red[1] + red[2] + red[3]);
        __syncthreads();
    }
}

__device__ __forceinline__ void proc4(f4 s, f4 w, f4 a0, f4 a1, f4 a2,
                                      float& rn2, float& d0, float& d1, float& d2) {
    float r;
    r = elu1(w.x * s.x); rn2 = fmaf(r, r, rn2); d0 = fmaf(r, a0.x, d0); d1 = fmaf(r, a1.x, d1); d2 = fmaf(r, a2.x, d2);
    r = elu1(w.y * s.y); rn2 = fmaf(r, r, rn2); d0 = fmaf(r, a0.y, d0); d1 = fmaf(r, a1.y, d1); d2 = fmaf(r, a2.y, d2);
    r = elu1(w.z * s.z); rn2 = fmaf(r, r, rn2); d0 = fmaf(r, a0.z, d0); d1 = fmaf(r, a1.z, d1); d2 = fmaf(r, a2.z, d2);
    r = elu1(w.w * s.w); rn2 = fmaf(r, r, rn2); d0 = fmaf(r, a0.w, d0); d1 = fmaf(r, a1.w, d1); d2 = fmaf(r, a2.w, d2);
}

// One wave per row (proven form). Lane l owns cols [4l,4l+4) and
// [256+4l,256+4l+4): weight + 3 ave rows in registers; butterfly reduce;
// lanes 0..2 write the softmax row.
__global__ __launch_bounds__(256) void cosine_softmax_kernel(
        const float* __restrict__ seq, const float* __restrict__ weight,
        const float* __restrict__ ave, const float* __restrict__ an3,
        float* __restrict__ out) {
    const int lane = threadIdx.x & 63;
    const int wv = threadIdx.x >> 6;
    const int b0 = 4 * lane, b1 = 256 + 4 * lane;
    const f4 w0 = *(const f4*)(weight + b0);
    const f4 w1 = *(const f4*)(weight + b1);
    const f4 a00 = *(const f4*)(ave + 0 * DCOLS + b0);
    const f4 a01 = *(const f4*)(ave + 0 * DCOLS + b1);
    const f4 a10 = *(const f4*)(ave + 1 * DCOLS + b0);
    const f4 a11 = *(const f4*)(ave + 1 * DCOLS + b1);
    const f4 a20 = *(const f4*)(ave + 2 * DCOLS + b0);
    const f4 a21 = *(const f4*)(ave + 2 * DCOLS + b1);
    const float an0 = an3[0], an1 = an3[1], an2 = an3[2];
    for (int row = blockIdx.x * 4 + wv; row < NROWS; row += CGRID * 4) {
        const float* srow = seq + (size_t)row * DCOLS;
        f4 s0 = *(const f4*)(srow + b0);
        f4 s1 = *(const f4*)(srow + b1);
        float rn2 = 0.f, d0 = 0.f, d1 = 0.f, d2 = 0.f;
        proc4(s0, w0, a00, a10, a20, rn2, d0, d1, d2);
        proc4(s1, w1, a01, a11, a21, rn2, d0, d1, d2);
        #pragma unroll
        for (int o = 32; o; o >>= 1) {
            rn2 += __shfl_xor(rn2, o);
            d0  += __shfl_xor(d0, o);
            d1  += __shfl_xor(d1, o);
            d2  += __shfl_xor(d2, o);
        }
        if (lane < 3) {
            const float rn = sqrtf(rn2);
            float s0v = d0 / fmaxf(rn * an0, 1e-8f);
            float s1v = d1 / fmaxf(rn * an1, 1e-8f);
            float s2v = d2 / fmaxf(rn * an2, 1e-8f);
            float m = fmaxf(s0v, fmaxf(s1v, s2v));
            float e0 = __expf(s0v - m), e1 = __expf(s1v - m), e2 = __expf(s2v - m);
            float einv = 1.0f / (e0 + e1 + e2);
            float p = (lane == 0) ? e0 : (lane == 1 ? e1 : e2);
            out[(size_t)row * 3 + lane] = p * einv;
        }
    }
}

extern "C" void kernel_launch(void* const* d_in, const int* in_sizes, int n_in,
                              void* d_out, int out_size, void* d_ws, size_t ws_size,
                              hipStream_t stream) {
    const float* seq     = (const float*)d_in[0];
    const float* feature = (const float*)d_in[1];
    const int*   labels  = (const int*)d_in[2];
    const float* weight  = (const float*)d_in[3];
    const int*   train   = (const int*)d_in[4];
    float* out = (float*)d_out;

    float* sums = (float*)d_ws;           // 1536 floats
    float* ave  = sums + NC * DCOLS;      // 1536 floats
    float* an   = ave + NC * DCOLS;       // 3 floats

    zero_sums<<<6, 256, 0, stream>>>(sums);
    segsum_kernel<<<SGRID, 256, 0, stream>>>(feature, seq, weight, labels, train, sums);
    ave_norm_kernel<<<1, 256, 0, stream>>>(sums, ave, an);
    cosine_softmax_kernel<<<CGRID, 256, 0, stream>>>(seq, weight, ave, an, out);
}

// Round 9
// 246.544 us; speedup vs baseline: 1.2970x; 1.2970x over previous
//
#include <hip/hip_runtime.h>
#include <math.h>

#define NROWS 200000
#define HALFR 100000
#define DCOLS 512
#define NC 3
#define SGRID 1024
#define CGRID 2048

typedef float f4 __attribute__((ext_vector_type(4)));

__device__ __forceinline__ float elu1(float x) {
    return x > 0.0f ? x : __expf(x) - 1.0f;
}

__device__ __forceinline__ f4 elu4(f4 w, f4 x) {
    f4 r;
    r.x = elu1(w.x * x.x); r.y = elu1(w.y * x.y);
    r.z = elu1(w.z * x.z); r.w = elu1(w.w * x.w);
    return r;
}

__global__ void zero_sums(float* sums) {
    int t = blockIdx.x * blockDim.x + threadIdx.x;
    if (t < NC * DCOLS) sums[t] = 0.0f;
}

// Wave-per-row segment sum (clone of the proven cosine access pattern):
// one wave reads a full contiguous 2KB row as 2x dwordx4; the row label is
// wave-uniform -> uniform branch into one of 3 accumulator pairs. Two
// interleaved row cursors (rA, rB=rA+100000) give 4 independent 16B loads
// in flight per iteration. Cross-wave reduce once in LDS; block atomics.
__global__ __launch_bounds__(256) void segsum_kernel(
        const float* __restrict__ feature, const float* __restrict__ seq,
        const float* __restrict__ weight, const int* __restrict__ labels,
        const int* __restrict__ train, float* __restrict__ sums) {
    const int lane = threadIdx.x & 63;
    const int wv = threadIdx.x >> 6;
    const int b0 = 4 * lane, b1 = 256 + 4 * lane;
    const int tr = train[0];
    const float* __restrict__ src = tr ? seq : feature;
    f4 wA = (f4)(0.f), wB = (f4)(0.f);
    if (tr) { wA = *(const f4*)(weight + b0); wB = *(const f4*)(weight + b1); }

    f4 a0A = (f4)(0.f), a0B = (f4)(0.f);
    f4 a1A = (f4)(0.f), a1B = (f4)(0.f);
    f4 a2A = (f4)(0.f), a2B = (f4)(0.f);

    const int stride = SGRID * 4;
    for (int rA = blockIdx.x * 4 + wv; rA < HALFR; rA += stride) {
        const int rB = rA + HALFR;
        const int la = labels[rA];
        const int lb = labels[rB];
        const float* pA = src + (size_t)rA * DCOLS;
        const float* pB = src + (size_t)rB * DCOLS;
        f4 xA0 = *(const f4*)(pA + b0);
        f4 xA1 = *(const f4*)(pA + b1);
        f4 xB0 = *(const f4*)(pB + b0);
        f4 xB1 = *(const f4*)(pB + b1);
        if (tr) {
            xA0 = elu4(wA, xA0); xA1 = elu4(wB, xA1);
            xB0 = elu4(wA, xB0); xB1 = elu4(wB, xB1);
        }
        if (la == 0)      { a0A += xA0; a0B += xA1; }
        else if (la == 1) { a1A += xA0; a1B += xA1; }
        else              { a2A += xA0; a2B += xA1; }
        if (lb == 0)      { a0A += xB0; a0B += xB1; }
        else if (lb == 1) { a1A += xB0; a1B += xB1; }
        else              { a2A += xB0; a2B += xB1; }
    }

    // cross-wave reduce (once): red[wave][class][lane][half]
    __shared__ f4 red[4][NC][64][2];
    red[wv][0][lane][0] = a0A; red[wv][0][lane][1] = a0B;
    red[wv][1][lane][0] = a1A; red[wv][1][lane][1] = a1B;
    red[wv][2][lane][0] = a2A; red[wv][2][lane][1] = a2B;
    __syncthreads();
    if (wv < NC) {   // wave wv reduces class wv
        f4 sA = red[0][wv][lane][0] + red[1][wv][lane][0]
              + red[2][wv][lane][0] + red[3][wv][lane][0];
        f4 sB = red[0][wv][lane][1] + red[1][wv][lane][1]
              + red[2][wv][lane][1] + red[3][wv][lane][1];
        atomicAdd(&sums[wv * DCOLS + b0 + 0], sA.x);
        atomicAdd(&sums[wv * DCOLS + b0 + 1], sA.y);
        atomicAdd(&sums[wv * DCOLS + b0 + 2], sA.z);
        atomicAdd(&sums[wv * DCOLS + b0 + 3], sA.w);
        atomicAdd(&sums[wv * DCOLS + b1 + 0], sB.x);
        atomicAdd(&sums[wv * DCOLS + b1 + 1], sB.y);
        atomicAdd(&sums[wv * DCOLS + b1 + 2], sB.z);
        atomicAdd(&sums[wv * DCOLS + b1 + 3], sB.w);
    }
}

// ave = sums / (N/2); an[c] = ||ave[c]||. Single block.
__global__ __launch_bounds__(256) void ave_norm_kernel(
        const float* __restrict__ sums, float* __restrict__ ave,
        float* __restrict__ an) {
    __shared__ float red[4];
    const int t = threadIdx.x, lane = t & 63, wv = t >> 6;
    const float inv = 1.0f / (float)(NROWS / 2);
    for (int c = 0; c < NC; ++c) {
        float p = 0.0f;
        for (int j = t; j < DCOLS; j += 256) {
            float v = sums[c * DCOLS + j] * inv;
            ave[c * DCOLS + j] = v;
            p += v * v;
        }
        for (int o = 32; o; o >>= 1) p += __shfl_xor(p, o);
        if (lane == 0) red[wv] = p;
        __syncthreads();
        if (t == 0) an[c] = sqrtf(red[0] + red[1] + red[2] + red[3]);
        __syncthreads();
    }
}

__device__ __forceinline__ void proc4(f4 s, f4 w, f4 a0, f4 a1, f4 a2,
                                      float& rn2, float& d0, float& d1, float& d2) {
    float r;
    r = elu1(w.x * s.x); rn2 = fmaf(r, r, rn2); d0 = fmaf(r, a0.x, d0); d1 = fmaf(r, a1.x, d1); d2 = fmaf(r, a2.x, d2);
    r = elu1(w.y * s.y); rn2 = fmaf(r, r, rn2); d0 = fmaf(r, a0.y, d0); d1 = fmaf(r, a1.y, d1); d2 = fmaf(r, a2.y, d2);
    r = elu1(w.z * s.z); rn2 = fmaf(r, r, rn2); d0 = fmaf(r, a0.z, d0); d1 = fmaf(r, a1.z, d1); d2 = fmaf(r, a2.z, d2);
    r = elu1(w.w * s.w); rn2 = fmaf(r, r, rn2); d0 = fmaf(r, a0.w, d0); d1 = fmaf(r, a1.w, d1); d2 = fmaf(r, a2.w, d2);
}

// One wave per row (proven form). Lane l owns cols [4l,4l+4) and
// [256+4l,256+4l+4): weight + 3 ave rows in registers; butterfly reduce;
// lanes 0..2 write the softmax row.
__global__ __launch_bounds__(256) void cosine_softmax_kernel(
        const float* __restrict__ seq, const float* __restrict__ weight,
        const float* __restrict__ ave, const float* __restrict__ an3,
        float* __restrict__ out) {
    const int lane = threadIdx.x & 63;
    const int wv = threadIdx.x >> 6;
    const int b0 = 4 * lane, b1 = 256 + 4 * lane;
    const f4 w0 = *(const f4*)(weight + b0);
    const f4 w1 = *(const f4*)(weight + b1);
    const f4 a00 = *(const f4*)(ave + 0 * DCOLS + b0);
    const f4 a01 = *(const f4*)(ave + 0 * DCOLS + b1);
    const f4 a10 = *(const f4*)(ave + 1 * DCOLS + b0);
    const f4 a11 = *(const f4*)(ave + 1 * DCOLS + b1);
    const f4 a20 = *(const f4*)(ave + 2 * DCOLS + b0);
    const f4 a21 = *(const f4*)(ave + 2 * DCOLS + b1);
    const float an0 = an3[0], an1 = an3[1], an2 = an3[2];
    for (int row = blockIdx.x * 4 + wv; row < NROWS; row += CGRID * 4) {
        const float* srow = seq + (size_t)row * DCOLS;
        f4 s0 = *(const f4*)(srow + b0);
        f4 s1 = *(const f4*)(srow + b1);
        float rn2 = 0.f, d0 = 0.f, d1 = 0.f, d2 = 0.f;
        proc4(s0, w0, a00, a10, a20, rn2, d0, d1, d2);
        proc4(s1, w1, a01, a11, a21, rn2, d0, d1, d2);
        #pragma unroll
        for (int o = 32; o; o >>= 1) {
            rn2 += __shfl_xor(rn2, o);
            d0  += __shfl_xor(d0, o);
            d1  += __shfl_xor(d1, o);
            d2  += __shfl_xor(d2, o);
        }
        if (lane < 3) {
            const float rn = sqrtf(rn2);
            float s0v = d0 / fmaxf(rn * an0, 1e-8f);
            float s1v = d1 / fmaxf(rn * an1, 1e-8f);
            float s2v = d2 / fmaxf(rn * an2, 1e-8f);
            float m = fmaxf(s0v, fmaxf(s1v, s2v));
            float e0 = __expf(s0v - m), e1 = __expf(s1v - m), e2 = __expf(s2v - m);
            float einv = 1.0f / (e0 + e1 + e2);
            float p = (lane == 0) ? e0 : (lane == 1 ? e1 : e2);
            out[(size_t)row * 3 + lane] = p * einv;
        }
    }
}

extern "C" void kernel_launch(void* const* d_in, const int* in_sizes, int n_in,
                              void* d_out, int out_size, void* d_ws, size_t ws_size,
                              hipStream_t stream) {
    const float* seq     = (const float*)d_in[0];
    const float* feature = (const float*)d_in[1];
    const int*   labels  = (const int*)d_in[2];
    const float* weight  = (const float*)d_in[3];
    const int*   train   = (const int*)d_in[4];
    float* out = (float*)d_out;

    float* sums = (float*)d_ws;           // 1536 floats
    float* ave  = sums + NC * DCOLS;      // 1536 floats
    float* an   = ave + NC * DCOLS;       // 3 floats

    zero_sums<<<6, 256, 0, stream>>>(sums);
    segsum_kernel<<<SGRID, 256, 0, stream>>>(feature, seq, weight, labels, train, sums);
    ave_norm_kernel<<<1, 256, 0, stream>>>(sums, ave, an);
    cosine_softmax_kernel<<<CGRID, 256, 0, stream>>>(seq, weight, ave, an, out);
}